// Round 4
// baseline (625.994 us; speedup 1.0000x reference)
//
#include <hip/hip_runtime.h>
#include <hip/hip_bf16.h>
#include <cstdint>

// GraphSAGEMean: x = relu chain of 4 linears over N rows; agg = row-mean of E.
// Persistent-block fused kernel: E -> LDS (bf16) -> 4 MFMA layers -> out.
// Weights pre-transposed to [out][in] bf16 in d_ws by prep_kernel.
//
// R1: ROWS 128->64 (4 blocks/CU). Occupancy 19.7->40.5%, dur flat -> not
//     occupancy-bound.
// R2: batched E loads in C++ -> compiler re-sank them (VGPR stayed 64); dur
//     294us == hbm_bytes/hbm_gbps at 16% BW -> latency-bound. MfmaUtil(12.8%)
//     x dur == 37us == peak-rate MFMA floor -> kernel is 85% stall.
// R3: inline-asm prefetch -> container failed; construct unsound (pending-load
//     registers invisible to allocator). Removed.
// R4: (a) persistent blocks, next tile's 16 E-row loads interleaved as PLAIN
//     loads into layer-1's k-loop (compiler-visible -> correct counted vmcnt);
//     (b) launch_bounds(256,2) -> 256-VGPR cap; hand 1-ahead double-buffered
//     weight/act fragment pipeline (a[2][MB], b[2][4], static indices);
//     (c) nontemporal stores for out_x/out_agg so 103MB of streaming writes
//     stop evicting the 448KB L2-resident weight set (suspected cause of
//     weight-load L2 misses AND the 2x WRITE_SIZE amplification).

#define N_ROWS 200000
#define O_DIM  128
#define ROWS   64          // rows per tile; 3125 * 64 == 200000 exactly
#define PITCH  264         // 256 + 8 bf16 pad
#define NTILES 3125
#define GRID   512         // persistent blocks: exactly 2 per CU

typedef short bf16x8 __attribute__((ext_vector_type(8)));   // 8 bf16 = 4 VGPRs
typedef float f32x4  __attribute__((ext_vector_type(4)));

__device__ __forceinline__ unsigned short rne_bf16(float f) {
  unsigned int u = __float_as_uint(f);
  u += 0x7FFFu + ((u >> 16) & 1u);      // round-to-nearest-even
  return (unsigned short)(u >> 16);
}

// Transpose + bf16-cast all weights into ws: Wt[o][i] = bf16(W[i][o]).
// Layout in ws (ushort elems): Wt1 @0, Wt2 @65536, Wt3 @131072, Wto @196608.
__global__ __launch_bounds__(256) void prep_kernel(
    const float* __restrict__ W1, const float* __restrict__ W2,
    const float* __restrict__ W3, const float* __restrict__ Wo,
    unsigned short* __restrict__ wt) {
  const int b = blockIdx.x;
  const int t = threadIdx.x;
  if (b < 256) {
    wt[b * 256 + t] = rne_bf16(W1[t * 256 + b]);
  } else if (b < 512) {
    const int o = b - 256;
    wt[65536 + o * 256 + t] = rne_bf16(W2[t * 256 + o]);
  } else if (b < 768) {
    const int o = b - 512;
    wt[131072 + o * 256 + t] = rne_bf16(W3[t * 256 + o]);
  } else {
    const int o = b - 768;
    wt[196608 + o * 256 + t] = rne_bf16(Wo[t * 128 + o]);
  }
}

// One layer, operand-swapped: D[m=out_ch][n=row] = sum_k Wt[m][k] * act[n][k].
// A-frag (Wt) from global (L2-resident), B-frag (act) from LDS; 1-ahead
// double-buffered fragment pipeline. If PF, also interleave the NEXT tile's
// 16 E-row loads (2 per k-step) into the loop: they sit behind the weight
// loads in the vmcnt FIFO and drain for free at this layer's end barrier.
template <int MB, bool RELU, bool LAST, bool PF>
__device__ __forceinline__ void do_layer(
    const unsigned short* __restrict__ wt, const float* __restrict__ bias,
    float* __restrict__ out_x, long row0, unsigned short* act,
    int wave, int lane, const float* __restrict__ Enext, f32x4* stage) {
  const int lc   = lane & 15;
  const int quad = lane >> 4;
  const int m_base = wave * (MB * 16);   // 64 ch/wave (L1-3), 32 (L4)

  f32x4 acc[MB][4];
#pragma unroll
  for (int mb = 0; mb < MB; ++mb)
#pragma unroll
    for (int nb = 0; nb < 4; ++nb)
      acc[mb][nb] = (f32x4){0.f, 0.f, 0.f, 0.f};

  // fragment pipeline registers (all indices compile-time after unroll)
  bf16x8 a[2][MB], b[2][4];
#pragma unroll
  for (int nb = 0; nb < 4; ++nb)
    b[0][nb] = *(const bf16x8*)&act[(nb * 16 + lc) * PITCH + 8 * quad];
#pragma unroll
  for (int mb = 0; mb < MB; ++mb)
    a[0][mb] = *(const bf16x8*)&wt[(m_base + mb * 16 + lc) * 256 + 8 * quad];

#pragma unroll
  for (int ks = 0; ks < 8; ++ks) {
    const int cur = ks & 1, nxt = cur ^ 1;
    if (PF) {  // 2 E rows of the next tile per k-step; rows i*4+wave
      const int i0 = 2 * ks;
      stage[i0]     = *(const f32x4*)(Enext + (i0 * 4 + wave) * 256 + lane * 4);
      stage[i0 + 1] = *(const f32x4*)(Enext + ((i0 + 1) * 4 + wave) * 256 + lane * 4);
    }
    if (ks < 7) {
      const int k0 = (ks + 1) * 32;
#pragma unroll
      for (int nb = 0; nb < 4; ++nb)
        b[nxt][nb] = *(const bf16x8*)&act[(nb * 16 + lc) * PITCH + k0 + 8 * quad];
#pragma unroll
      for (int mb = 0; mb < MB; ++mb)
        a[nxt][mb] = *(const bf16x8*)&wt[(m_base + mb * 16 + lc) * 256 + k0 + 8 * quad];
    }
#pragma unroll
    for (int mb = 0; mb < MB; ++mb)
#pragma unroll
      for (int nb = 0; nb < 4; ++nb)
        acc[mb][nb] = __builtin_amdgcn_mfma_f32_16x16x32_bf16(a[cur][mb], b[cur][nb],
                                                              acc[mb][nb], 0, 0, 0);
  }
  __syncthreads();   // all B-frag reads of act done before overwrite

#pragma unroll
  for (int mb = 0; mb < MB; ++mb) {
    const int ch = m_base + mb * 16 + 4 * quad;
    f32x4 bb = *(const f32x4*)(bias + ch);
#pragma unroll
    for (int nb = 0; nb < 4; ++nb) {
      f32x4 v = acc[mb][nb] + bb;
      if (RELU) {
#pragma unroll
        for (int j = 0; j < 4; ++j) v[j] = fmaxf(v[j], 0.f);
      }
      const int r = nb * 16 + lc;
      if (!LAST) {
        ushort4 h;
        h.x = rne_bf16(v[0]); h.y = rne_bf16(v[1]);
        h.z = rne_bf16(v[2]); h.w = rne_bf16(v[3]);
        *(ushort4*)&act[r * PITCH + ch] = h;          // 8B LDS write
      } else {
        const long gr = row0 + r;
        __builtin_nontemporal_store(v, (f32x4*)&out_x[gr * O_DIM + ch]);
      }
    }
  }
  __syncthreads();   // writes visible before next phase
}

__global__ __launch_bounds__(256, 2) void sage_kernel(
    const float* __restrict__ E,
    const float* __restrict__ b1, const float* __restrict__ b2,
    const float* __restrict__ b3, const float* __restrict__ bo,
    const unsigned short* __restrict__ wts,
    float* __restrict__ out_x, float* __restrict__ out_agg) {
  __shared__ __align__(16) unsigned short act[ROWS * PITCH];  // 33792 B

  const int t    = threadIdx.x;
  const int wave = t >> 6;          // 0..3
  const int lane = t & 63;

  f32x4 stage[16];                  // 16 E rows/wave of one tile (64 VGPRs)

  int tile = blockIdx.x;
  // Prologue: fetch tile 0 for this slot (batched issue, one-time cost).
  {
    const float* Ep = E + (long)tile * ROWS * 256;
#pragma unroll
    for (int i = 0; i < 16; ++i)
      stage[i] = *(const f32x4*)(Ep + (i * 4 + wave) * 256 + lane * 4);
  }

  while (true) {
    const long row0 = (long)tile * ROWS;

    // Consume stage -> bf16 act tile + fused row-mean (output 1).
#pragma unroll
    for (int i = 0; i < 16; ++i) {
      const int r = i * 4 + wave;
      ushort4 h;
      h.x = rne_bf16(stage[i][0]); h.y = rne_bf16(stage[i][1]);
      h.z = rne_bf16(stage[i][2]); h.w = rne_bf16(stage[i][3]);
      *(ushort4*)&act[r * PITCH + lane * 4] = h;
      float s = stage[i][0] + stage[i][1] + stage[i][2] + stage[i][3];
      s += __shfl_down(s, 32);
      s += __shfl_down(s, 16);
      s += __shfl_down(s, 8);
      s += __shfl_down(s, 4);
      s += __shfl_down(s, 2);
      s += __shfl_down(s, 1);
      if (lane == 0)
        __builtin_nontemporal_store(s * (1.0f / 256.0f), &out_agg[row0 + r]);
    }
    __syncthreads();

    const int next = tile + GRID;
    const bool has_next = next < NTILES;       // uniform per block
    const float* Enext = E + (long)next * ROWS * 256;

    if (has_next)
      do_layer<4, true, false, true >(wts, b1, nullptr, row0, act, wave, lane,
                                      Enext, stage);
    else
      do_layer<4, true, false, false>(wts, b1, nullptr, row0, act, wave, lane,
                                      nullptr, stage);
    do_layer<4, true,  false, false>(wts + 65536,  b2, nullptr, row0, act, wave,
                                     lane, nullptr, stage);
    do_layer<4, true,  false, false>(wts + 131072, b3, nullptr, row0, act, wave,
                                     lane, nullptr, stage);
    do_layer<2, false, true,  false>(wts + 196608, bo, out_x,   row0, act, wave,
                                     lane, nullptr, stage);

    if (!has_next) break;
    tile = next;
  }
}

extern "C" void kernel_launch(void* const* d_in, const int* in_sizes, int n_in,
                              void* d_out, int out_size, void* d_ws, size_t ws_size,
                              hipStream_t stream) {
  const float* E  = (const float*)d_in[0];
  // d_in[1] = adj_keys: mathematically unused (identity gather in reference)
  const float* W1 = (const float*)d_in[2];
  const float* b1 = (const float*)d_in[3];
  const float* W2 = (const float*)d_in[4];
  const float* b2 = (const float*)d_in[5];
  const float* W3 = (const float*)d_in[6];
  const float* b3 = (const float*)d_in[7];
  const float* Wo = (const float*)d_in[8];
  const float* bo = (const float*)d_in[9];

  float* out_x   = (float*)d_out;
  float* out_agg = out_x + (size_t)N_ROWS * O_DIM;
  unsigned short* wts = (unsigned short*)d_ws;   // 458752 B used

  prep_kernel<<<896, 256, 0, stream>>>(W1, W2, W3, Wo, wts);

  sage_kernel<<<GRID, 256, 0, stream>>>(E, b1, b2, b3, bo, wts, out_x, out_agg);
}

// Round 5
// 523.769 us; speedup vs baseline: 1.1952x; 1.1952x over previous
//
#include <hip/hip_runtime.h>
#include <hip/hip_bf16.h>
#include <cstdint>

// GraphSAGEMean: x = relu chain of 4 linears over N rows; agg = row-mean of E.
//
// R5 structure: persistent blocks (512 thr, 8 waves, 1 block/CU), weights
// staged per 128-ch half-panel (64KB) into LDS via global_load_lds, ping-pong
// across 2 slots so staging hides under compute. k-loop reads ONLY LDS.
// act tile: 64 rows x 256 ch bf16, PITCH 256 + XOR swizzle (T2). Weight slots
// get the same swizzle via inverse-swizzled global source (rule 21).
// LDS = 32768 (act) + 2*65536 (wbuf) = 163840 B exact fit.
// H0's B-fragments are register-cached (128 VGPR) and reused in H1 -> halves
// LDS reads AND lets H1 write the layer output into act with no extra buffer.
//
// History: R1 occupancy x2 -> flat (not occupancy-bound). R2 MLP batching ->
// +6% only (compiler re-sank loads). R4 NT stores -> FETCH x4 (partial-line
// RMW), reverted. Constant across all: MfmaUtil*dur == 37us == MFMA floor;
// stall source = per-k-step global weight loads. R5 removes them.

#define N_ROWS 200000
#define O_DIM  128
#define ROWS   64          // rows per tile; 3125 * 64 == 200000 exactly
#define NTILES 3125
#define GRIDP  256         // persistent blocks: 1 per CU

typedef short bf16x8 __attribute__((ext_vector_type(8)));   // 8 bf16 = 4 VGPRs
typedef float f32x4  __attribute__((ext_vector_type(4)));

__device__ __forceinline__ unsigned short rne_bf16(float f) {
  unsigned int u = __float_as_uint(f);
  u += 0x7FFFu + ((u >> 16) & 1u);      // round-to-nearest-even
  return (unsigned short)(u >> 16);
}

// XOR swizzle on byte offsets of 512B-row tiles: spreads the 16 lanes of a
// column-slice read across 8 distinct 16B slots -> 2-way bank alias (free).
// Involution; swizzle bits come only from the row index (>=bit9), so
// swz(swz(b)) == b and read/write sides agree.
__device__ __forceinline__ int swz(int b) { return b ^ (((b >> 9) & 7) << 4); }

// Transpose + bf16-cast all weights into ws: Wt[o][i] = bf16(W[i][o]).
// Layout (ushort elems): Wt1 @0, Wt2 @65536, Wt3 @131072, Wto @196608.
// Half-panels (128 rows x 256 k = 65536 B) are contiguous.
__global__ __launch_bounds__(256) void prep_kernel(
    const float* __restrict__ W1, const float* __restrict__ W2,
    const float* __restrict__ W3, const float* __restrict__ Wo,
    unsigned short* __restrict__ wt) {
  const int b = blockIdx.x;
  const int t = threadIdx.x;
  if (b < 256) {
    wt[b * 256 + t] = rne_bf16(W1[t * 256 + b]);
  } else if (b < 512) {
    const int o = b - 256;
    wt[65536 + o * 256 + t] = rne_bf16(W2[t * 256 + o]);
  } else if (b < 768) {
    const int o = b - 512;
    wt[131072 + o * 256 + t] = rne_bf16(W3[t * 256 + o]);
  } else {
    const int o = b - 768;
    wt[196608 + o * 256 + t] = rne_bf16(Wo[t * 128 + o]);
  }
}

// K-loop over K=256 for one 128-ch half-panel. Wave w owns ch_local w*16+lc.
// A-frags from the (swizzled) weight slot, B-frags from act (FILL) or the
// register cache (!FILL). All LDS, no global.
template <bool FILL>
__device__ __forceinline__ void half_mm(
    const unsigned short* __restrict__ wslot, const char* __restrict__ actb,
    bf16x8 bc[8][4], f32x4 acc[4], int wave, int lc, int quad) {
  const char* wb = (const char*)wslot;
#pragma unroll
  for (int ks = 0; ks < 8; ++ks) {
    const int k0 = ks * 32;
    const bf16x8 afr =
        *(const bf16x8*)(wb + swz((wave * 16 + lc) * 512 + k0 * 2 + 16 * quad));
    if (FILL) {
#pragma unroll
      for (int nb = 0; nb < 4; ++nb)
        bc[ks][nb] = *(const bf16x8*)(actb +
                       swz((nb * 16 + lc) * 512 + k0 * 2 + 16 * quad));
    }
#pragma unroll
    for (int nb = 0; nb < 4; ++nb)
      acc[nb] = __builtin_amdgcn_mfma_f32_16x16x32_bf16(afr, bc[ks][nb],
                                                        acc[nb], 0, 0, 0);
  }
}

// bias + relu + bf16 round, write both half-panels' outputs into act.
__device__ __forceinline__ void layer_store_act(
    char* __restrict__ actb, const float* __restrict__ bias,
    f32x4 acc0[4], f32x4 acc1[4], int wave, int lc, int quad) {
#pragma unroll
  for (int h = 0; h < 2; ++h) {
    f32x4* acc = h ? acc1 : acc0;
    const int ch = h * 128 + wave * 16 + 4 * quad;
    const f32x4 bb = *(const f32x4*)(bias + ch);
#pragma unroll
    for (int nb = 0; nb < 4; ++nb) {
      f32x4 v = acc[nb] + bb;
#pragma unroll
      for (int j = 0; j < 4; ++j) v[j] = fmaxf(v[j], 0.f);
      const int r = nb * 16 + lc;
      ushort4 hq;
      hq.x = rne_bf16(v[0]); hq.y = rne_bf16(v[1]);
      hq.z = rne_bf16(v[2]); hq.w = rne_bf16(v[3]);
      *(ushort4*)(actb + swz(r * 512 + ch * 2)) = hq;   // 8B, swizzle-safe
    }
  }
}

__global__ __launch_bounds__(512, 2) void sage_kernel(
    const float* __restrict__ E,
    const float* __restrict__ b1, const float* __restrict__ b2,
    const float* __restrict__ b3, const float* __restrict__ bo,
    const unsigned short* __restrict__ wts,
    float* __restrict__ out_x, float* __restrict__ out_agg) {
  __shared__ __align__(16) unsigned short act[16384];       // 32 KB
  __shared__ __align__(16) unsigned short wbuf[2][32768];   // 2 x 64 KB
  char* actb = (char*)act;

  const int t    = threadIdx.x;
  const int wave = t >> 6;          // 0..7
  const int lane = t & 63;
  const int lc   = lane & 15;
  const int quad = lane >> 4;

  // Async half-panel stage: 64KB = 8 rounds x 8 waves x 64 lanes x 16B.
  // LDS dest is wave-uniform (HW adds lane*16); global src is per-lane and
  // pre-inverse-swizzled so the LINEAR LDS write lands swizzled (rule 21).
  auto stage_issue = [&](const unsigned short* wsrc, unsigned short* slot) {
#pragma unroll
    for (int rnd = 0; rnd < 8; ++rnd) {
      const int lds_rel = rnd * 8192 + wave * 1024 + lane * 16;
      __builtin_amdgcn_global_load_lds(
          (const unsigned int*)((const char*)wsrc + swz(lds_rel)),
          (unsigned int*)((char*)slot + rnd * 8192 + wave * 1024),
          16, 0, 0);
    }
  };

  bf16x8 bc[8][4];                  // H0 B-frag cache, reused in H1 (128 VGPR)
  f32x4 acc0[4], acc1[4];

  int tile = blockIdx.x;
  stage_issue(wts, wbuf[0]);        // W1H0 for tile 0
  int sel = 1;                      // next stage target slot

  for (;;) {
    const long row0 = (long)tile * ROWS;

    __syncthreads();   // act free (prev L4 done reading); pending stage drained

    // ---- phase 0: E tile -> act (bf16, swizzled) + fused row-mean ----
    {
      f32x4 st[8];
#pragma unroll
      for (int i = 0; i < 8; ++i)
        st[i] = *(const f32x4*)(E + (row0 + i * 8 + wave) * 256 + lane * 4);
#pragma unroll
      for (int i = 0; i < 8; ++i) {
        const int r = i * 8 + wave;
        ushort4 h;
        h.x = rne_bf16(st[i][0]); h.y = rne_bf16(st[i][1]);
        h.z = rne_bf16(st[i][2]); h.w = rne_bf16(st[i][3]);
        *(ushort4*)(actb + swz(r * 512 + lane * 8)) = h;
        float s = st[i][0] + st[i][1] + st[i][2] + st[i][3];
        s += __shfl_down(s, 32);
        s += __shfl_down(s, 16);
        s += __shfl_down(s, 8);
        s += __shfl_down(s, 4);
        s += __shfl_down(s, 2);
        s += __shfl_down(s, 1);
        if (lane == 0) out_agg[row0 + r] = s * (1.0f / 256.0f);
      }
    }
    __syncthreads();   // act visible; (W_L H0 already resident)

    // ---- layers 1..3: two half-panel phases each ----
    const unsigned short* wl = wts;
    const float* bias[3] = {b1, b2, b3};
#pragma unroll 1
    for (int L = 0; L < 3; ++L) {
      // phase A: stage H1 -> wbuf[sel]; compute H0 from wbuf[sel^1]; fill bc.
      stage_issue(wl + 32768, wbuf[sel]);
#pragma unroll
      for (int nb = 0; nb < 4; ++nb) acc0[nb] = (f32x4){0.f, 0.f, 0.f, 0.f};
      half_mm<true>(wbuf[sel ^ 1], actb, bc, acc0, wave, lc, quad);
      __syncthreads();   // H1 resident; all reads of wbuf[sel^1] done
      sel ^= 1;

      // phase B: stage next layer's H0 (or Wo) -> wbuf[sel]; compute H1 from
      // bc cache (no act reads!) then overwrite act with this layer's output.
      stage_issue(L < 2 ? wl + 65536 : wts + 196608, wbuf[sel]);
#pragma unroll
      for (int nb = 0; nb < 4; ++nb) acc1[nb] = (f32x4){0.f, 0.f, 0.f, 0.f};
      half_mm<false>(wbuf[sel ^ 1], actb, bc, acc1, wave, lc, quad);
      layer_store_act(actb, bias[L], acc0, acc1, wave, lc, quad);
      __syncthreads();   // act(L out) visible; next panel resident
      sel ^= 1;
      wl += 65536;
    }

    // ---- layer 4 (Wo, one half-panel, no relu) + out store ----
    const int nxt = tile + GRIDP;
    const bool has_next = nxt < NTILES;
    if (has_next) stage_issue(wts, wbuf[sel]);   // next tile's W1H0
#pragma unroll
    for (int nb = 0; nb < 4; ++nb) acc0[nb] = (f32x4){0.f, 0.f, 0.f, 0.f};
    half_mm<true>(wbuf[sel ^ 1], actb, bc, acc0, wave, lc, quad);
    sel ^= 1;
    {
      const int ch = wave * 16 + 4 * quad;
      const f32x4 bb = *(const f32x4*)(bo + ch);
#pragma unroll
      for (int nb = 0; nb < 4; ++nb) {
        f32x4 v = acc0[nb] + bb;
        const long gr = row0 + nb * 16 + lc;
        *(f32x4*)&out_x[gr * O_DIM + ch] = v;    // 16B plain store
      }
    }

    if (!has_next) break;
    tile = nxt;
  }
}

extern "C" void kernel_launch(void* const* d_in, const int* in_sizes, int n_in,
                              void* d_out, int out_size, void* d_ws, size_t ws_size,
                              hipStream_t stream) {
  const float* E  = (const float*)d_in[0];
  // d_in[1] = adj_keys: mathematically unused (identity gather in reference)
  const float* W1 = (const float*)d_in[2];
  const float* b1 = (const float*)d_in[3];
  const float* W2 = (const float*)d_in[4];
  const float* b2 = (const float*)d_in[5];
  const float* W3 = (const float*)d_in[6];
  const float* b3 = (const float*)d_in[7];
  const float* Wo = (const float*)d_in[8];
  const float* bo = (const float*)d_in[9];

  float* out_x   = (float*)d_out;
  float* out_agg = out_x + (size_t)N_ROWS * O_DIM;
  unsigned short* wts = (unsigned short*)d_ws;   // 458752 B used

  prep_kernel<<<896, 256, 0, stream>>>(W1, W2, W3, Wo, wts);

  sage_kernel<<<GRIDP, 512, 0, stream>>>(E, b1, b2, b3, bo, wts, out_x, out_agg);
}